// Round 1
// baseline (1062.859 us; speedup 1.0000x reference)
//
#include <hip/hip_runtime.h>

// Problem dims (fixed by reference): N=50000, E=800000, D_IN=128, D_H=64, B=64
constexpr int DI = 128;
constexpr int DH = 64;
constexpr int NB = 64;

__global__ void k_deg_init(float* __restrict__ deg, int n) {
    int i = blockIdx.x * 256 + threadIdx.x;
    if (i < n) deg[i] = 1.0f;  // self-loop
}

__global__ void k_deg_acc(const int* __restrict__ dst, float* __restrict__ deg, int e) {
    int i = blockIdx.x * 256 + threadIdx.x;
    if (i < e) atomicAdd(&deg[dst[i]], 1.0f);
}

__global__ void k_dinv(float* __restrict__ deg, int n) {
    int i = blockIdx.x * 256 + threadIdx.x;
    if (i < n) deg[i] = 1.0f / sqrtf(deg[i]);
}

// h = act(in) @ W ; agg = h * dinv^2  (self-loop init)
// act = identity (layer 1) or relu(v + bprev) (layers 2,3; folded previous epilogue)
// One wave per node (lane = output feature j). In-place in==agg is safe:
// each wave reads only its own node's row and writes only its own node's row,
// and the write is data-dependent on all the reads.
template <int DIN, bool RELU>
__global__ void k_matmul(const float* __restrict__ in, const float* __restrict__ W,
                         const float* __restrict__ bprev, const float* __restrict__ dinv,
                         float* __restrict__ h, float* __restrict__ agg, int n) {
    __shared__ float Wl[DIN * DH];
    __shared__ float bl[DIN];
    for (int i = threadIdx.x; i < DIN * DH; i += 256) Wl[i] = W[i];
    if (RELU)
        for (int i = threadIdx.x; i < DIN; i += 256) bl[i] = bprev[i];
    __syncthreads();

    int node = blockIdx.x * 4 + (threadIdx.x >> 6);
    int j = threadIdx.x & 63;
    if (node >= n) return;

    const float* row = in + (size_t)node * DIN;
    float acc = 0.0f;
#pragma unroll 8
    for (int k = 0; k < DIN; ++k) {
        float v = row[k];  // wave-uniform broadcast load
        if (RELU) v = fmaxf(v + bl[k], 0.0f);
        acc = fmaf(v, Wl[k * DH + j], acc);
    }
    float dv = dinv[node];
    size_t o = (size_t)node * DH + j;
    h[o] = acc;
    agg[o] = acc * dv * dv;
}

// One wave per edge: lane j handles feature j. src/dst wave-uniform,
// gather + atomic fully coalesced (256B contiguous per edge).
__global__ void k_scatter(const int* __restrict__ src, const int* __restrict__ dst,
                          const float* __restrict__ dinv, const float* __restrict__ h,
                          float* __restrict__ agg, int e) {
    long long idx = (long long)blockIdx.x * 256 + threadIdx.x;
    int ed = (int)(idx >> 6);
    int j = (int)(idx & 63);
    if (ed >= e) return;
    int s = src[ed];
    int d = dst[ed];
    float w = dinv[s] * dinv[d];
    atomicAdd(&agg[(size_t)d * DH + j], h[(size_t)s * DH + j] * w);
}

// pooled-sum + count via atomics; epilogue relu(agg + b3) folded in.
__global__ void k_pool(const float* __restrict__ agg, const float* __restrict__ b3,
                       const int* __restrict__ batch, float* __restrict__ pool,
                       float* __restrict__ cnt, int n) {
    int node = blockIdx.x * 4 + (threadIdx.x >> 6);
    int j = threadIdx.x & 63;
    if (node >= n) return;
    float v = fmaxf(agg[(size_t)node * DH + j] + b3[j], 0.0f);
    int b = batch[node];
    atomicAdd(&pool[b * DH + j], v);
    if (j == 0) atomicAdd(&cnt[b], 1.0f);
}

// out[b] = (pool[b,:] / max(cnt,1)) . Wfc + bfc   — one wave per batch
__global__ void k_fc(const float* __restrict__ pool, const float* __restrict__ cnt,
                     const float* __restrict__ Wfc, const float* __restrict__ bfc,
                     float* __restrict__ out) {
    int b = blockIdx.x;
    int j = threadIdx.x;  // 64 threads = 1 wave
    float c = fmaxf(cnt[b], 1.0f);
    float p = (pool[b * DH + j] / c) * Wfc[j];
#pragma unroll
    for (int off = 32; off; off >>= 1) p += __shfl_down(p, off);
    if (j == 0) out[b] = p + bfc[0];
}

extern "C" void kernel_launch(void* const* d_in, const int* in_sizes, int n_in,
                              void* d_out, int out_size, void* d_ws, size_t ws_size,
                              hipStream_t stream) {
    const float* x    = (const float*)d_in[0];
    const int* ei     = (const int*)d_in[1];
    const int* batch  = (const int*)d_in[2];
    const float* W1   = (const float*)d_in[3];
    const float* b1   = (const float*)d_in[4];
    const float* W2   = (const float*)d_in[5];
    const float* b2   = (const float*)d_in[6];
    const float* W3   = (const float*)d_in[7];
    const float* b3   = (const float*)d_in[8];
    const float* Wfc  = (const float*)d_in[9];
    const float* bfc  = (const float*)d_in[10];
    float* out = (float*)d_out;

    const int n = in_sizes[0] / DI;      // 50000
    const int e = in_sizes[1] / 2;       // 800000
    const int* src = ei;
    const int* dst = ei + e;

    float* dinv = (float*)d_ws;          // n
    float* h    = dinv + n;              // n*DH
    float* agg  = h + (size_t)n * DH;    // n*DH
    float* pool = agg + (size_t)n * DH;  // NB*DH
    float* cnt  = pool + NB * DH;        // NB

    const int nb256 = (n + 255) / 256;
    const int eb256 = (e + 255) / 256;
    const int mmb = (n + 3) / 4;
    const int scb = (int)(((long long)e * 64 + 255) / 256);

    // degree (shared by all layers)
    k_deg_init<<<nb256, 256, 0, stream>>>(dinv, n);
    k_deg_acc<<<eb256, 256, 0, stream>>>(dst, dinv, e);
    k_dinv<<<nb256, 256, 0, stream>>>(dinv, n);

    // layer 1
    k_matmul<DI, false><<<mmb, 256, 0, stream>>>(x, W1, nullptr, dinv, h, agg, n);
    k_scatter<<<scb, 256, 0, stream>>>(src, dst, dinv, h, agg, e);
    // layer 2 (relu + b1 folded into matmul input)
    k_matmul<DH, true><<<mmb, 256, 0, stream>>>(agg, W2, b1, dinv, h, agg, n);
    k_scatter<<<scb, 256, 0, stream>>>(src, dst, dinv, h, agg, e);
    // layer 3
    k_matmul<DH, true><<<mmb, 256, 0, stream>>>(agg, W3, b2, dinv, h, agg, n);
    k_scatter<<<scb, 256, 0, stream>>>(src, dst, dinv, h, agg, e);

    // pool + fc (relu + b3 folded into pool)
    hipMemsetAsync(pool, 0, (NB * DH + NB) * sizeof(float), stream);
    k_pool<<<mmb, 256, 0, stream>>>(agg, b3, batch, pool, cnt, n);
    k_fc<<<NB, DH, 0, stream>>>(pool, cnt, Wfc, bfc, out);
}

// Round 2
// 739.055 us; speedup vs baseline: 1.4381x; 1.4381x over previous
//
#include <hip/hip_runtime.h>

// Problem dims (fixed by reference): N=50000, E=800000, D_IN=128, D_H=64, B=64
constexpr int DI = 128;
constexpr int DH = 64;
constexpr int NB = 64;
constexpr int PS = 8;   // pool split factor (blocks per batch segment)

__global__ void k_deg_init(float* __restrict__ deg, int n) {
    int i = blockIdx.x * 256 + threadIdx.x;
    if (i < n) deg[i] = 1.0f;  // self-loop
}

__global__ void k_deg_acc(const int* __restrict__ dst, float* __restrict__ deg, int e) {
    int i = blockIdx.x * 256 + threadIdx.x;
    if (i < e) atomicAdd(&deg[dst[i]], 1.0f);
}

__global__ void k_dinv(float* __restrict__ deg, int n) {
    int i = blockIdx.x * 256 + threadIdx.x;
    if (i < n) deg[i] = 1.0f / sqrtf(deg[i]);
}

// h = act(in) @ W ; agg = h * dinv^2  (self-loop init)
// act = identity (layer 1) or relu(v + bprev) (layers 2,3; folded previous epilogue)
// One wave per node (lane = output feature j). In-place in==agg is safe:
// each wave reads only its own node's row and writes only its own node's row.
template <int DIN, bool RELU>
__global__ void k_matmul(const float* __restrict__ in, const float* __restrict__ W,
                         const float* __restrict__ bprev, const float* __restrict__ dinv,
                         float* __restrict__ h, float* __restrict__ agg, int n) {
    __shared__ float Wl[DIN * DH];
    __shared__ float bl[DIN];
    for (int i = threadIdx.x; i < DIN * DH; i += 256) Wl[i] = W[i];
    if (RELU)
        for (int i = threadIdx.x; i < DIN; i += 256) bl[i] = bprev[i];
    __syncthreads();

    int node = blockIdx.x * 4 + (threadIdx.x >> 6);
    int j = threadIdx.x & 63;
    if (node >= n) return;

    const float* row = in + (size_t)node * DIN;
    float acc = 0.0f;
#pragma unroll 8
    for (int k = 0; k < DIN; ++k) {
        float v = row[k];  // wave-uniform broadcast load
        if (RELU) v = fmaxf(v + bl[k], 0.0f);
        acc = fmaf(v, Wl[k * DH + j], acc);
    }
    float dv = dinv[node];
    size_t o = (size_t)node * DH + j;
    h[o] = acc;
    agg[o] = acc * dv * dv;
}

// One wave per edge: lane j handles feature j. src/dst wave-uniform,
// gather + atomic fully coalesced (256B contiguous per edge).
__global__ void k_scatter(const int* __restrict__ src, const int* __restrict__ dst,
                          const float* __restrict__ dinv, const float* __restrict__ h,
                          float* __restrict__ agg, int e) {
    long long idx = (long long)blockIdx.x * 256 + threadIdx.x;
    int ed = (int)(idx >> 6);
    int j = (int)(idx & 63);
    if (ed >= e) return;
    int s = src[ed];
    int d = dst[ed];
    float w = dinv[s] * dinv[d];
    atomicAdd(&agg[(size_t)d * DH + j], h[(size_t)s * DH + j] * w);
}

__device__ __forceinline__ int lower_bound_batch(const int* __restrict__ batch, int n, int val) {
    int lo = 0, hi = n;
    while (lo < hi) {
        int mid = (lo + hi) >> 1;
        if (batch[mid] < val) lo = mid + 1; else hi = mid;
    }
    return lo;
}

// Atomic-free pool stage 1: batch is SORTED, so batch b owns contiguous nodes
// [lo,hi) found by binary search. Block (b,s) sums slice s of that range.
// Epilogue relu(agg + b3) folded in.
__global__ void k_pool_part(const float* __restrict__ agg, const float* __restrict__ b3,
                            const int* __restrict__ batch, float* __restrict__ part, int n) {
    int b = blockIdx.x / PS;
    int s = blockIdx.x % PS;
    int lo = lower_bound_batch(batch, n, b);
    int hi = lower_bound_batch(batch, n, b + 1);
    int len = hi - lo;
    int c0 = lo + (int)((long long)len * s / PS);
    int c1 = lo + (int)((long long)len * (s + 1) / PS);

    int j = threadIdx.x & 63;
    int w = threadIdx.x >> 6;
    float bj = b3[j];
    float acc = 0.0f;
    for (int node = c0 + w; node < c1; node += 4)
        acc += fmaxf(agg[(size_t)node * DH + j] + bj, 0.0f);

    __shared__ float red[4][DH];
    red[w][j] = acc;
    __syncthreads();
    if (w == 0)
        part[(b * PS + s) * DH + j] = red[0][j] + red[1][j] + red[2][j] + red[3][j];
}

// Stage 2 + FC: out[b] = (sum_s part[b,s,:] / max(cnt,1)) . Wfc + bfc
// cnt recomputed by binary search (no atomics). One wave per batch.
__global__ void k_fc(const float* __restrict__ part, const int* __restrict__ batch,
                     const float* __restrict__ Wfc, const float* __restrict__ bfc,
                     float* __restrict__ out, int n) {
    int b = blockIdx.x;
    int j = threadIdx.x;  // 64 threads = 1 wave
    int lo = lower_bound_batch(batch, n, b);
    int hi = lower_bound_batch(batch, n, b + 1);
    float c = fmaxf((float)(hi - lo), 1.0f);
    float p = 0.0f;
#pragma unroll
    for (int s = 0; s < PS; ++s) p += part[(b * PS + s) * DH + j];
    p = (p / c) * Wfc[j];
#pragma unroll
    for (int off = 32; off; off >>= 1) p += __shfl_down(p, off);
    if (j == 0) out[b] = p + bfc[0];
}

extern "C" void kernel_launch(void* const* d_in, const int* in_sizes, int n_in,
                              void* d_out, int out_size, void* d_ws, size_t ws_size,
                              hipStream_t stream) {
    const float* x    = (const float*)d_in[0];
    const int* ei     = (const int*)d_in[1];
    const int* batch  = (const int*)d_in[2];
    const float* W1   = (const float*)d_in[3];
    const float* b1   = (const float*)d_in[4];
    const float* W2   = (const float*)d_in[5];
    const float* b2   = (const float*)d_in[6];
    const float* W3   = (const float*)d_in[7];
    const float* b3   = (const float*)d_in[8];
    const float* Wfc  = (const float*)d_in[9];
    const float* bfc  = (const float*)d_in[10];
    float* out = (float*)d_out;

    const int n = in_sizes[0] / DI;      // 50000
    const int e = in_sizes[1] / 2;       // 800000
    const int* src = ei;
    const int* dst = ei + e;

    float* dinv = (float*)d_ws;          // n
    float* h    = dinv + n;              // n*DH
    float* agg  = h + (size_t)n * DH;    // n*DH
    float* part = agg + (size_t)n * DH;  // NB*PS*DH

    const int nb256 = (n + 255) / 256;
    const int eb256 = (e + 255) / 256;
    const int mmb = (n + 3) / 4;
    const int scb = (int)(((long long)e * 64 + 255) / 256);

    // degree (shared by all layers)
    k_deg_init<<<nb256, 256, 0, stream>>>(dinv, n);
    k_deg_acc<<<eb256, 256, 0, stream>>>(dst, dinv, e);
    k_dinv<<<nb256, 256, 0, stream>>>(dinv, n);

    // layer 1
    k_matmul<DI, false><<<mmb, 256, 0, stream>>>(x, W1, nullptr, dinv, h, agg, n);
    k_scatter<<<scb, 256, 0, stream>>>(src, dst, dinv, h, agg, e);
    // layer 2 (relu + b1 folded into matmul input)
    k_matmul<DH, true><<<mmb, 256, 0, stream>>>(agg, W2, b1, dinv, h, agg, n);
    k_scatter<<<scb, 256, 0, stream>>>(src, dst, dinv, h, agg, e);
    // layer 3
    k_matmul<DH, true><<<mmb, 256, 0, stream>>>(agg, W3, b2, dinv, h, agg, n);
    k_scatter<<<scb, 256, 0, stream>>>(src, dst, dinv, h, agg, e);

    // pool + fc (relu + b3 folded into pool; fully atomic-free)
    k_pool_part<<<NB * PS, 256, 0, stream>>>(agg, b3, batch, part, n);
    k_fc<<<NB, DH, 0, stream>>>(part, batch, Wfc, bfc, out, n);
}

// Round 4
// 472.491 us; speedup vs baseline: 2.2495x; 1.5642x over previous
//
#include <hip/hip_runtime.h>

// Problem dims (fixed by reference): N=50000, E=800000, D_IN=128, D_H=64, B=64
constexpr int DI = 128;
constexpr int DH = 64;
constexpr int NB = 64;
constexpr int PS = 8;    // pool split factor
constexpr int SCB = 256; // scan block size

// ---------- CSR build ----------
__global__ void k_count(const int* __restrict__ dst, int* __restrict__ counts, int e) {
    int i = blockIdx.x * 256 + threadIdx.x;
    if (i < e) atomicAdd(&counts[dst[i]], 1);
}

// per-block exclusive scan; excl[i] = scan within block, bsum[b] = block total
__global__ void k_scan1(const int* __restrict__ counts, int* __restrict__ excl,
                        int* __restrict__ bsum, int n) {
    __shared__ int sd[SCB];
    int t = threadIdx.x;
    int i = blockIdx.x * SCB + t;
    int v = (i < n) ? counts[i] : 0;
    sd[t] = v;
    __syncthreads();
    for (int o = 1; o < SCB; o <<= 1) {
        int x = (t >= o) ? sd[t - o] : 0;
        __syncthreads();
        sd[t] += x;
        __syncthreads();
    }
    if (i < n) excl[i] = sd[t] - v;
    if (t == SCB - 1) bsum[blockIdx.x] = sd[t];
}

// single-block exclusive scan of block sums (grid-stride with carry)
__global__ void k_scan2(const int* __restrict__ bsum, int* __restrict__ boff, int g) {
    __shared__ int sd[256];
    __shared__ int carry;
    int t = threadIdx.x;
    if (t == 0) carry = 0;
    __syncthreads();
    for (int base = 0; base < g; base += 256) {
        int idx = base + t;
        int v = (idx < g) ? bsum[idx] : 0;
        sd[t] = v;
        __syncthreads();
        for (int o = 1; o < 256; o <<= 1) {
            int x = (t >= o) ? sd[t - o] : 0;
            __syncthreads();
            sd[t] += x;
            __syncthreads();
        }
        if (idx < g) boff[idx] = sd[t] - v + carry;
        __syncthreads();
        if (t == 0) carry += sd[255];
        __syncthreads();
    }
}

// off = global exclusive scan; cursor = copy; dinv = 1/sqrt(1+indeg)
// (1.0f/sqrtf, NOT rsqrtf — bit-matches the validated rounds' dinv)
__global__ void k_scan3(const int* __restrict__ counts, const int* __restrict__ excl,
                        const int* __restrict__ boff, int* __restrict__ off,
                        int* __restrict__ cursor, float* __restrict__ dinv, int n, int e) {
    int i = blockIdx.x * 256 + threadIdx.x;
    if (i < n) {
        int o = excl[i] + boff[i / SCB];
        off[i] = o;
        cursor[i] = o;
        dinv[i] = 1.0f / sqrtf(1.0f + (float)counts[i]);
    }
    if (i == n) off[n] = e;
}

__global__ void k_fill(const int* __restrict__ src, const int* __restrict__ dst,
                       int* __restrict__ cursor, int* __restrict__ adj, int e) {
    int i = blockIdx.x * 256 + threadIdx.x;
    if (i < e) {
        int p = atomicAdd(&cursor[dst[i]], 1);
        adj[p] = src[i];
    }
}

// sort each bucket ascending by src value -> deterministic summation order
// (bucket multiset is deterministic even though atomic fill order is not)
__global__ void k_sort(const int* __restrict__ off, int* __restrict__ adj, int n) {
    int d = blockIdx.x * 256 + threadIdx.x;
    if (d >= n) return;
    int a0 = off[d], a1 = off[d + 1];
    for (int i = a0 + 1; i < a1; ++i) {
        int key = adj[i];
        int j = i - 1;
        while (j >= a0 && adj[j] > key) { adj[j + 1] = adj[j]; --j; }
        adj[j + 1] = key;
    }
}

// ---------- layers ----------
// g = (act(in) @ W) * dinv   (pre-scaled so gather needs no per-edge dinv)
// act = identity (layer 1) or relu(v + bprev) (layers 2,3)
template <int DIN, bool RELU>
__global__ void k_matmul(const float* __restrict__ in, const float* __restrict__ W,
                         const float* __restrict__ bprev, const float* __restrict__ dinv,
                         float* __restrict__ g, int n) {
    __shared__ float Wl[DIN * DH];
    __shared__ float bl[DIN];
    for (int i = threadIdx.x; i < DIN * DH; i += 256) Wl[i] = W[i];
    if (RELU)
        for (int i = threadIdx.x; i < DIN; i += 256) bl[i] = bprev[i];
    __syncthreads();

    int node = blockIdx.x * 4 + (threadIdx.x >> 6);
    int j = threadIdx.x & 63;
    if (node >= n) return;

    const float* row = in + (size_t)node * DIN;
    float acc = 0.0f;
#pragma unroll 8
    for (int k = 0; k < DIN; ++k) {
        float v = row[k];  // wave-uniform broadcast load
        if (RELU) v = fmaxf(v + bl[k], 0.0f);
        acc = fmaf(v, Wl[k * DH + j], acc);
    }
    g[(size_t)node * DH + j] = acc * dinv[node];
}

// agg[d] = dv_d * ( g[d] + sum_{s in N(d)} g[s] )
//        = h[d]*dinv_d^2 + sum_s h[s]*dinv_s*dinv_d   (matches reference)
// NOTE: self term enters acc UNSCALED (bug fix vs round 3 which had g[d]*dv
// -> h*dinv^3). One wave per node, lane = feature; adj loads wave-uniform,
// g rows coalesced 256B.
__global__ void k_gather(const int* __restrict__ off, const int* __restrict__ adj,
                         const float* __restrict__ dinv, const float* __restrict__ g,
                         float* __restrict__ agg, int n) {
    int node = blockIdx.x * 4 + (threadIdx.x >> 6);
    int j = threadIdx.x & 63;
    if (node >= n) return;
    int a0 = off[node], a1 = off[node + 1];
    float dv = dinv[node];
    float acc = g[(size_t)node * DH + j];  // self-loop (dv applied at end)
    int a = a0;
    for (; a + 4 <= a1; a += 4) {
        int s0 = adj[a + 0], s1 = adj[a + 1], s2 = adj[a + 2], s3 = adj[a + 3];
        float v0 = g[(size_t)s0 * DH + j];
        float v1 = g[(size_t)s1 * DH + j];
        float v2 = g[(size_t)s2 * DH + j];
        float v3 = g[(size_t)s3 * DH + j];
        acc += v0 + v1 + v2 + v3;
    }
    for (; a < a1; ++a) acc += g[(size_t)adj[a] * DH + j];
    agg[(size_t)node * DH + j] = acc * dv;
}

// ---------- pool + fc ----------
__device__ __forceinline__ int lower_bound_batch(const int* __restrict__ batch, int n, int val) {
    int lo = 0, hi = n;
    while (lo < hi) {
        int mid = (lo + hi) >> 1;
        if (batch[mid] < val) lo = mid + 1; else hi = mid;
    }
    return lo;
}

__global__ void k_pool_part(const float* __restrict__ agg, const float* __restrict__ b3,
                            const int* __restrict__ batch, float* __restrict__ part, int n) {
    int b = blockIdx.x / PS;
    int s = blockIdx.x % PS;
    int lo = lower_bound_batch(batch, n, b);
    int hi = lower_bound_batch(batch, n, b + 1);
    int len = hi - lo;
    int c0 = lo + (int)((long long)len * s / PS);
    int c1 = lo + (int)((long long)len * (s + 1) / PS);

    int j = threadIdx.x & 63;
    int w = threadIdx.x >> 6;
    float bj = b3[j];
    float acc = 0.0f;
    for (int node = c0 + w; node < c1; node += 4)
        acc += fmaxf(agg[(size_t)node * DH + j] + bj, 0.0f);

    __shared__ float red[4][DH];
    red[w][j] = acc;
    __syncthreads();
    if (w == 0)
        part[(b * PS + s) * DH + j] = red[0][j] + red[1][j] + red[2][j] + red[3][j];
}

__global__ void k_fc(const float* __restrict__ part, const int* __restrict__ batch,
                     const float* __restrict__ Wfc, const float* __restrict__ bfc,
                     float* __restrict__ out, int n) {
    int b = blockIdx.x;
    int j = threadIdx.x;  // 64 threads = 1 wave
    int lo = lower_bound_batch(batch, n, b);
    int hi = lower_bound_batch(batch, n, b + 1);
    float c = fmaxf((float)(hi - lo), 1.0f);
    float p = 0.0f;
#pragma unroll
    for (int s = 0; s < PS; ++s) p += part[(b * PS + s) * DH + j];
    p = (p / c) * Wfc[j];
#pragma unroll
    for (int off = 32; off; off >>= 1) p += __shfl_down(p, off);
    if (j == 0) out[b] = p + bfc[0];
}

extern "C" void kernel_launch(void* const* d_in, const int* in_sizes, int n_in,
                              void* d_out, int out_size, void* d_ws, size_t ws_size,
                              hipStream_t stream) {
    const float* x    = (const float*)d_in[0];
    const int* ei     = (const int*)d_in[1];
    const int* batch  = (const int*)d_in[2];
    const float* W1   = (const float*)d_in[3];
    const float* b1   = (const float*)d_in[4];
    const float* W2   = (const float*)d_in[5];
    const float* b2   = (const float*)d_in[6];
    const float* W3   = (const float*)d_in[7];
    const float* b3   = (const float*)d_in[8];
    const float* Wfc  = (const float*)d_in[9];
    const float* bfc  = (const float*)d_in[10];
    float* out = (float*)d_out;

    const int n = in_sizes[0] / DI;  // 50000
    const int e = in_sizes[1] / 2;   // 800000
    const int* src = ei;
    const int* dst = ei + e;

    // workspace layout (all 4-byte elements)
    float* dinv   = (float*)d_ws;               // n
    float* h      = dinv + n;                   // n*DH
    float* agg    = h + (size_t)n * DH;         // n*DH
    float* part   = agg + (size_t)n * DH;       // NB*PS*DH
    int*   counts = (int*)(part + NB * PS * DH);// n
    int*   excl   = counts + n;                 // n
    int*   off    = excl + n;                   // n+1
    int*   cursor = off + n + 1;                // n
    int*   bsum   = cursor + n;                 // 256
    int*   boff   = bsum + 256;                 // 256
    int*   adj    = boff + 256;                 // e

    const int nb256 = (n + 255) / 256;
    const int eb256 = (e + 255) / 256;
    const int mmb   = (n + 3) / 4;
    const int sg    = (n + SCB - 1) / SCB;

    // ---- CSR build (shared by all 3 layers) ----
    hipMemsetAsync(counts, 0, (size_t)n * sizeof(int), stream);
    k_count<<<eb256, 256, 0, stream>>>(dst, counts, e);
    k_scan1<<<sg, SCB, 0, stream>>>(counts, excl, bsum, n);
    k_scan2<<<1, 256, 0, stream>>>(bsum, boff, sg);
    k_scan3<<<nb256 + 1, 256, 0, stream>>>(counts, excl, boff, off, cursor, dinv, n, e);
    k_fill<<<eb256, 256, 0, stream>>>(src, dst, cursor, adj, e);
    k_sort<<<nb256, 256, 0, stream>>>(off, adj, n);

    // ---- layers ----
    k_matmul<DI, false><<<mmb, 256, 0, stream>>>(x, W1, nullptr, dinv, h, n);
    k_gather<<<mmb, 256, 0, stream>>>(off, adj, dinv, h, agg, n);
    k_matmul<DH, true><<<mmb, 256, 0, stream>>>(agg, W2, b1, dinv, h, n);
    k_gather<<<mmb, 256, 0, stream>>>(off, adj, dinv, h, agg, n);
    k_matmul<DH, true><<<mmb, 256, 0, stream>>>(agg, W3, b2, dinv, h, n);
    k_gather<<<mmb, 256, 0, stream>>>(off, adj, dinv, h, agg, n);

    // ---- pool + fc ----
    k_pool_part<<<NB * PS, 256, 0, stream>>>(agg, b3, batch, part, n);
    k_fc<<<NB, DH, 0, stream>>>(part, batch, Wfc, bfc, out, n);
}

// Round 5
// 360.440 us; speedup vs baseline: 2.9488x; 1.3109x over previous
//
#include <hip/hip_runtime.h>

// Problem dims (fixed by reference): N=50000, E=800000, D_IN=128, D_H=64, B=64
constexpr int DI = 128;
constexpr int DH = 64;
constexpr int NB = 64;
constexpr int PS = 8;    // pool split factor
constexpr int SCB = 256; // scan block size

// ---------- CSR build ----------
__global__ void k_count(const int* __restrict__ dst, int* __restrict__ counts, int e) {
    int i = blockIdx.x * 256 + threadIdx.x;
    if (i < e) atomicAdd(&counts[dst[i]], 1);
}

// per-block exclusive scan; excl[i] = scan within block, bsum[b] = block total
__global__ void k_scan1(const int* __restrict__ counts, int* __restrict__ excl,
                        int* __restrict__ bsum, int n) {
    __shared__ int sd[SCB];
    int t = threadIdx.x;
    int i = blockIdx.x * SCB + t;
    int v = (i < n) ? counts[i] : 0;
    sd[t] = v;
    __syncthreads();
    for (int o = 1; o < SCB; o <<= 1) {
        int x = (t >= o) ? sd[t - o] : 0;
        __syncthreads();
        sd[t] += x;
        __syncthreads();
    }
    if (i < n) excl[i] = sd[t] - v;
    if (t == SCB - 1) bsum[blockIdx.x] = sd[t];
}

// single-block exclusive scan of block sums (grid-stride with carry)
__global__ void k_scan2(const int* __restrict__ bsum, int* __restrict__ boff, int g) {
    __shared__ int sd[256];
    __shared__ int carry;
    int t = threadIdx.x;
    if (t == 0) carry = 0;
    __syncthreads();
    for (int base = 0; base < g; base += 256) {
        int idx = base + t;
        int v = (idx < g) ? bsum[idx] : 0;
        sd[t] = v;
        __syncthreads();
        for (int o = 1; o < 256; o <<= 1) {
            int x = (t >= o) ? sd[t - o] : 0;
            __syncthreads();
            sd[t] += x;
            __syncthreads();
        }
        if (idx < g) boff[idx] = sd[t] - v + carry;
        __syncthreads();
        if (t == 0) carry += sd[255];
        __syncthreads();
    }
}

// off = global exclusive scan; cursor = copy; dinv = 1/sqrt(1+indeg)
__global__ void k_scan3(const int* __restrict__ counts, const int* __restrict__ excl,
                        const int* __restrict__ boff, int* __restrict__ off,
                        int* __restrict__ cursor, float* __restrict__ dinv, int n, int e) {
    int i = blockIdx.x * 256 + threadIdx.x;
    if (i < n) {
        int o = excl[i] + boff[i / SCB];
        off[i] = o;
        cursor[i] = o;
        dinv[i] = 1.0f / sqrtf(1.0f + (float)counts[i]);
    }
    if (i == n) off[n] = e;
}

__global__ void k_fill(const int* __restrict__ src, const int* __restrict__ dst,
                       int* __restrict__ cursor, int* __restrict__ adj, int e) {
    int i = blockIdx.x * 256 + threadIdx.x;
    if (i < e) {
        int p = atomicAdd(&cursor[dst[i]], 1);
        adj[p] = src[i];
    }
}

// Wave-parallel rank sort: one wave per node bucket. Lane l holds key adj[a0+l];
// rank = #{m: key_m < key_l or (== and m < l)}; write adj[a0+rank]=key.
// Tie-break by slot index is fill-order-dependent, but tied keys are IDENTICAL
// values, so the resulting array (and all downstream sums) stay deterministic.
__global__ void k_sort(const int* __restrict__ off, int* __restrict__ adj, int n) {
    int node = blockIdx.x * 4 + (threadIdx.x >> 6);
    if (node >= n) return;
    int lane = threadIdx.x & 63;
    int a0 = off[node], a1 = off[node + 1];
    int deg = a1 - a0;
    if (deg <= 1) return;
    if (deg <= 64) {
        int key = (lane < deg) ? adj[a0 + lane] : 0x7fffffff;
        int rank = 0;
        for (int m = 0; m < deg; ++m) {
            int km = __shfl(key, m);
            rank += (km < key) || (km == key && m < lane);
        }
        if (lane < deg) adj[a0 + rank] = key;
    } else if (lane == 0) {  // fallback, astronomically rare for random graphs
        for (int i = a0 + 1; i < a1; ++i) {
            int key = adj[i];
            int j = i - 1;
            while (j >= a0 && adj[j] > key) { adj[j + 1] = adj[j]; --j; }
            adj[j + 1] = key;
        }
    }
}

// ---------- layers ----------
// g = (act(in) @ W) * dinv.  One wave computes 4 nodes (lane = output feature j).
// Node rows staged in REGISTERS (coalesced), row[k] broadcast via v_readlane
// (SGPR, VALU pipe) -> no per-k global loads, no ds_bpermute. Per-node fma
// order identical to the validated round-4 kernel.
template <int DIN, bool RELU>
__global__ __launch_bounds__(256) void k_matmul(const float* __restrict__ in,
                                                const float* __restrict__ W,
                                                const float* __restrict__ bprev,
                                                const float* __restrict__ dinv,
                                                float* __restrict__ g, int n) {
    constexpr int H = DIN / 64;
    __shared__ float Wl[DIN * DH];
    for (int i = threadIdx.x; i < DIN * DH; i += 256) Wl[i] = W[i];
    __syncthreads();

    int j = threadIdx.x & 63;
    int wid = threadIdx.x >> 6;
    int node0 = blockIdx.x * 16 + wid * 4;
    if (node0 >= n) return;
    int nv = min(4, n - node0);

    float bj[H];
    if (RELU) {
#pragma unroll
        for (int h = 0; h < H; ++h) bj[h] = bprev[h * 64 + j];
    }

    float r[4][H];
    float dv[4];
#pragma unroll
    for (int nn = 0; nn < 4; ++nn) {
        int node = node0 + ((nn < nv) ? nn : 0);
        dv[nn] = dinv[node];
#pragma unroll
        for (int h = 0; h < H; ++h) {
            float v = in[(size_t)node * DIN + h * 64 + j];
            if (RELU) v = fmaxf(v + bj[h], 0.0f);
            r[nn][h] = v;
        }
    }

    float acc[4] = {0.f, 0.f, 0.f, 0.f};
#pragma unroll
    for (int h = 0; h < H; ++h) {
#pragma unroll
        for (int kk = 0; kk < 64; ++kk) {
            float w = Wl[(h * 64 + kk) * DH + j];
#pragma unroll
            for (int nn = 0; nn < 4; ++nn) {
                float b = __int_as_float(
                    __builtin_amdgcn_readlane(__float_as_int(r[nn][h]), kk));
                acc[nn] = fmaf(b, w, acc[nn]);
            }
        }
    }
#pragma unroll
    for (int nn = 0; nn < 4; ++nn)
        if (nn < nv) g[(size_t)(node0 + nn) * DH + j] = acc[nn] * dv[nn];
}

// agg[d] = dv_d * ( g[d] + sum_{s in N(d)} g[s] )
// float4 layout: 16 lanes cover a 64-float row; the 4 lane-groups each fetch a
// different source row per load instruction (4 rows per wave-load, unroll 2 ->
// 8 rows in flight). Deterministic fixed partition + xor-shfl tree combine.
__global__ __launch_bounds__(256) void k_gather(const int* __restrict__ off,
                                                const int* __restrict__ adj,
                                                const float* __restrict__ dinv,
                                                const float4* __restrict__ g4,
                                                float4* __restrict__ agg4, int n) {
    int node = blockIdx.x * 4 + (threadIdx.x >> 6);
    if (node >= n) return;
    int lane = threadIdx.x & 63;
    int grp = lane >> 4, sub = lane & 15;
    int a0 = off[node], a1 = off[node + 1];

    float ax = 0.f, ay = 0.f, az = 0.f, aw = 0.f;
    for (int a = a0; a < a1; a += 8) {
        int i0 = a + grp, i1 = a + 4 + grp;
        int s0 = adj[i0 < a1 ? i0 : a0];
        int s1 = adj[i1 < a1 ? i1 : a0];
        float4 x0 = g4[(size_t)s0 * 16 + sub];
        float4 x1 = g4[(size_t)s1 * 16 + sub];
        if (i0 < a1) { ax += x0.x; ay += x0.y; az += x0.z; aw += x0.w; }
        if (i1 < a1) { ax += x1.x; ay += x1.y; az += x1.z; aw += x1.w; }
    }
#pragma unroll
    for (int m = 16; m <= 32; m <<= 1) {
        ax += __shfl_xor(ax, m);
        ay += __shfl_xor(ay, m);
        az += __shfl_xor(az, m);
        aw += __shfl_xor(aw, m);
    }
    float4 self = g4[(size_t)node * 16 + sub];
    float dvv = dinv[node];
    if (lane < 16) {
        float4 r;
        r.x = (ax + self.x) * dvv;
        r.y = (ay + self.y) * dvv;
        r.z = (az + self.z) * dvv;
        r.w = (aw + self.w) * dvv;
        agg4[(size_t)node * 16 + sub] = r;
    }
}

// ---------- pool + fc ----------
__device__ __forceinline__ int lower_bound_batch(const int* __restrict__ batch, int n, int val) {
    int lo = 0, hi = n;
    while (lo < hi) {
        int mid = (lo + hi) >> 1;
        if (batch[mid] < val) lo = mid + 1; else hi = mid;
    }
    return lo;
}

__global__ void k_pool_part(const float* __restrict__ agg, const float* __restrict__ b3,
                            const int* __restrict__ batch, float* __restrict__ part, int n) {
    int b = blockIdx.x / PS;
    int s = blockIdx.x % PS;
    int lo = lower_bound_batch(batch, n, b);
    int hi = lower_bound_batch(batch, n, b + 1);
    int len = hi - lo;
    int c0 = lo + (int)((long long)len * s / PS);
    int c1 = lo + (int)((long long)len * (s + 1) / PS);

    int j = threadIdx.x & 63;
    int w = threadIdx.x >> 6;
    float bj = b3[j];
    float acc = 0.0f;
    for (int node = c0 + w; node < c1; node += 4)
        acc += fmaxf(agg[(size_t)node * DH + j] + bj, 0.0f);

    __shared__ float red[4][DH];
    red[w][j] = acc;
    __syncthreads();
    if (w == 0)
        part[(b * PS + s) * DH + j] = red[0][j] + red[1][j] + red[2][j] + red[3][j];
}

__global__ void k_fc(const float* __restrict__ part, const int* __restrict__ batch,
                     const float* __restrict__ Wfc, const float* __restrict__ bfc,
                     float* __restrict__ out, int n) {
    int b = blockIdx.x;
    int j = threadIdx.x;  // 64 threads = 1 wave
    int lo = lower_bound_batch(batch, n, b);
    int hi = lower_bound_batch(batch, n, b + 1);
    float c = fmaxf((float)(hi - lo), 1.0f);
    float p = 0.0f;
#pragma unroll
    for (int s = 0; s < PS; ++s) p += part[(b * PS + s) * DH + j];
    p = (p / c) * Wfc[j];
#pragma unroll
    for (int off = 32; off; off >>= 1) p += __shfl_down(p, off);
    if (j == 0) out[b] = p + bfc[0];
}

extern "C" void kernel_launch(void* const* d_in, const int* in_sizes, int n_in,
                              void* d_out, int out_size, void* d_ws, size_t ws_size,
                              hipStream_t stream) {
    const float* x    = (const float*)d_in[0];
    const int* ei     = (const int*)d_in[1];
    const int* batch  = (const int*)d_in[2];
    const float* W1   = (const float*)d_in[3];
    const float* b1   = (const float*)d_in[4];
    const float* W2   = (const float*)d_in[5];
    const float* b2   = (const float*)d_in[6];
    const float* W3   = (const float*)d_in[7];
    const float* b3   = (const float*)d_in[8];
    const float* Wfc  = (const float*)d_in[9];
    const float* bfc  = (const float*)d_in[10];
    float* out = (float*)d_out;

    const int n = in_sizes[0] / DI;  // 50000
    const int e = in_sizes[1] / 2;   // 800000
    const int* src = ei;
    const int* dst = ei + e;

    // workspace layout (all 4-byte elements; h/agg 16B-aligned for float4)
    float* dinv   = (float*)d_ws;               // n
    float* h      = dinv + n;                   // n*DH   (offset 200000B, 16B-aligned)
    float* agg    = h + (size_t)n * DH;         // n*DH
    float* part   = agg + (size_t)n * DH;       // NB*PS*DH
    int*   counts = (int*)(part + NB * PS * DH);// n
    int*   excl   = counts + n;                 // n
    int*   off    = excl + n;                   // n+1
    int*   cursor = off + n + 1;                // n
    int*   bsum   = cursor + n;                 // 256
    int*   boff   = bsum + 256;                 // 256
    int*   adj    = boff + 256;                 // e

    const int nb256 = (n + 255) / 256;
    const int eb256 = (e + 255) / 256;
    const int wb4   = (n + 3) / 4;    // 1 wave per node kernels
    const int mmb   = (n + 15) / 16;  // matmul: 4 waves x 4 nodes
    const int sg    = (n + SCB - 1) / SCB;

    // ---- CSR build (shared by all 3 layers) ----
    hipMemsetAsync(counts, 0, (size_t)n * sizeof(int), stream);
    k_count<<<eb256, 256, 0, stream>>>(dst, counts, e);
    k_scan1<<<sg, SCB, 0, stream>>>(counts, excl, bsum, n);
    k_scan2<<<1, 256, 0, stream>>>(bsum, boff, sg);
    k_scan3<<<nb256 + 1, 256, 0, stream>>>(counts, excl, boff, off, cursor, dinv, n, e);
    k_fill<<<eb256, 256, 0, stream>>>(src, dst, cursor, adj, e);
    k_sort<<<wb4, 256, 0, stream>>>(off, adj, n);

    // ---- layers ----
    k_matmul<DI, false><<<mmb, 256, 0, stream>>>(x, W1, nullptr, dinv, h, n);
    k_gather<<<wb4, 256, 0, stream>>>(off, adj, dinv, (const float4*)h, (float4*)agg, n);
    k_matmul<DH, true><<<mmb, 256, 0, stream>>>(agg, W2, b1, dinv, h, n);
    k_gather<<<wb4, 256, 0, stream>>>(off, adj, dinv, (const float4*)h, (float4*)agg, n);
    k_matmul<DH, true><<<mmb, 256, 0, stream>>>(agg, W3, b2, dinv, h, n);
    k_gather<<<wb4, 256, 0, stream>>>(off, adj, dinv, (const float4*)h, (float4*)agg, n);

    // ---- pool + fc ----
    k_pool_part<<<NB * PS, 256, 0, stream>>>(agg, b3, batch, part, n);
    k_fc<<<NB, DH, 0, stream>>>(part, batch, Wfc, bfc, out, n);
}

// Round 6
// 303.384 us; speedup vs baseline: 3.5033x; 1.1881x over previous
//
#include <hip/hip_runtime.h>

// Problem dims (fixed by reference): N=50000, E=800000, D_IN=128, D_H=64, B=64
constexpr int DI = 128;
constexpr int DH = 64;
constexpr int NB = 64;
constexpr int PS = 8;    // pool split factor
constexpr int SCB = 256; // scan block size

// ---------- CSR build ----------
__global__ void k_count(const int* __restrict__ dst, int* __restrict__ counts, int e) {
    int i = blockIdx.x * 256 + threadIdx.x;
    if (i < e) atomicAdd(&counts[dst[i]], 1);
}

// per-block exclusive scan; excl[i] = scan within block, bsum[b] = block total
__global__ void k_scan1(const int* __restrict__ counts, int* __restrict__ excl,
                        int* __restrict__ bsum, int n) {
    __shared__ int sd[SCB];
    int t = threadIdx.x;
    int i = blockIdx.x * SCB + t;
    int v = (i < n) ? counts[i] : 0;
    sd[t] = v;
    __syncthreads();
    for (int o = 1; o < SCB; o <<= 1) {
        int x = (t >= o) ? sd[t - o] : 0;
        __syncthreads();
        sd[t] += x;
        __syncthreads();
    }
    if (i < n) excl[i] = sd[t] - v;
    if (t == SCB - 1) bsum[blockIdx.x] = sd[t];
}

// single-block exclusive scan of block sums (grid-stride with carry)
__global__ void k_scan2(const int* __restrict__ bsum, int* __restrict__ boff, int g) {
    __shared__ int sd[256];
    __shared__ int carry;
    int t = threadIdx.x;
    if (t == 0) carry = 0;
    __syncthreads();
    for (int base = 0; base < g; base += 256) {
        int idx = base + t;
        int v = (idx < g) ? bsum[idx] : 0;
        sd[t] = v;
        __syncthreads();
        for (int o = 1; o < 256; o <<= 1) {
            int x = (t >= o) ? sd[t - o] : 0;
            __syncthreads();
            sd[t] += x;
            __syncthreads();
        }
        if (idx < g) boff[idx] = sd[t] - v + carry;
        __syncthreads();
        if (t == 0) carry += sd[255];
        __syncthreads();
    }
}

// off = global exclusive scan; cursor = copy; dinv = 1/sqrt(1+indeg)
__global__ void k_scan3(const int* __restrict__ counts, const int* __restrict__ excl,
                        const int* __restrict__ boff, int* __restrict__ off,
                        int* __restrict__ cursor, float* __restrict__ dinv, int n, int e) {
    int i = blockIdx.x * 256 + threadIdx.x;
    if (i < n) {
        int o = excl[i] + boff[i / SCB];
        off[i] = o;
        cursor[i] = o;
        dinv[i] = 1.0f / sqrtf(1.0f + (float)counts[i]);
    }
    if (i == n) off[n] = e;
}

__global__ void k_fill(const int* __restrict__ src, const int* __restrict__ dst,
                       int* __restrict__ cursor, int* __restrict__ adj, int e) {
    int i = blockIdx.x * 256 + threadIdx.x;
    if (i < e) {
        int p = atomicAdd(&cursor[dst[i]], 1);
        adj[p] = src[i];
    }
}

// Wave-parallel rank sort: one wave per node bucket (deterministic result:
// tied keys are identical values).
__global__ void k_sort(const int* __restrict__ off, int* __restrict__ adj, int n) {
    int node = blockIdx.x * 4 + (threadIdx.x >> 6);
    if (node >= n) return;
    int lane = threadIdx.x & 63;
    int a0 = off[node], a1 = off[node + 1];
    int deg = a1 - a0;
    if (deg <= 1) return;
    if (deg <= 64) {
        int key = (lane < deg) ? adj[a0 + lane] : 0x7fffffff;
        int rank = 0;
        for (int m = 0; m < deg; ++m) {
            int km = __shfl(key, m);
            rank += (km < key) || (km == key && m < lane);
        }
        if (lane < deg) adj[a0 + rank] = key;
    } else if (lane == 0) {  // fallback, astronomically rare for random graphs
        for (int i = a0 + 1; i < a1; ++i) {
            int key = adj[i];
            int j = i - 1;
            while (j >= a0 && adj[j] > key) { adj[j + 1] = adj[j]; --j; }
            adj[j + 1] = key;
        }
    }
}

// ---------- layers ----------
__device__ __forceinline__ void fma4(float4& acc, float s, const float4& w) {
    acc.x = fmaf(s, w.x, acc.x);
    acc.y = fmaf(s, w.y, acc.y);
    acc.z = fmaf(s, w.z, acc.z);
    acc.w = fmaf(s, w.w, acc.w);
}

// g = (act(in) @ W) * dinv, LDS-tiled register-blocked GEMM.
// Block: 64 nodes x 64 feats, 256 threads as 16x16, 4x4 outputs/thread.
// W staged [K][64] (b128 reads, conflict-free); A staged node-major [64][68]
// (pad 68 -> A reads are 16-lane broadcasts, <=2-way bank alias = free).
// K=128 staged in two 64-col phases (LDS 49.4KB); K=64 single phase.
// act = identity (layer 1) or relu(v + bprev) folded into A staging.
// Per-output fma order: k ascending (same as validated rounds).
template <int K, bool RELU>
__global__ __launch_bounds__(256) void k_matmul(const float4* __restrict__ in4,
                                                const float4* __restrict__ W4,
                                                const float4* __restrict__ b4,
                                                const float* __restrict__ dinv,
                                                float4* __restrict__ g4, int n) {
    __shared__ float4 Wl[K * 16];    // [K][64] floats
    __shared__ float4 Al[64 * 17];   // [64][68] floats (pad 4)
    const int t = threadIdx.x;
    for (int i = t; i < K * 16; i += 256) Wl[i] = W4[i];

    const int tx = t & 15;          // feature group: 4*tx .. 4*tx+3
    const int ty = t >> 4;          // node group:    4*ty .. 4*ty+3
    const int node0 = blockIdx.x * 64;
    constexpr int K4 = K / 4;

    float4 acc0 = {0,0,0,0}, acc1 = {0,0,0,0}, acc2 = {0,0,0,0}, acc3 = {0,0,0,0};

#pragma unroll
    for (int ph = 0; ph < K / 64; ++ph) {
        __syncthreads();  // also covers initial W staging
#pragma unroll
        for (int s = 0; s < 4; ++s) {
            int i = t + s * 256;          // 64 rows x 16 float4
            int r = i >> 4, k4 = i & 15;
            int node = node0 + r;
            if (node >= n) node = n - 1;  // clamp (dup rows harmless)
            float4 v = in4[(size_t)node * K4 + ph * 16 + k4];
            if (RELU) {
                float4 bb = b4[ph * 16 + k4];
                v.x = fmaxf(v.x + bb.x, 0.f);
                v.y = fmaxf(v.y + bb.y, 0.f);
                v.z = fmaxf(v.z + bb.z, 0.f);
                v.w = fmaxf(v.w + bb.w, 0.f);
            }
            Al[r * 17 + k4] = v;
        }
        __syncthreads();
#pragma unroll 4
        for (int k4 = 0; k4 < 16; ++k4) {
            float4 a0 = Al[(4 * ty + 0) * 17 + k4];
            float4 a1 = Al[(4 * ty + 1) * 17 + k4];
            float4 a2 = Al[(4 * ty + 2) * 17 + k4];
            float4 a3 = Al[(4 * ty + 3) * 17 + k4];
            const float4* wrow = &Wl[(ph * 64 + 4 * k4) * 16 + tx];
            float4 w0 = wrow[0];
            float4 w1 = wrow[16];
            float4 w2 = wrow[32];
            float4 w3 = wrow[48];
            fma4(acc0, a0.x, w0); fma4(acc0, a0.y, w1); fma4(acc0, a0.z, w2); fma4(acc0, a0.w, w3);
            fma4(acc1, a1.x, w0); fma4(acc1, a1.y, w1); fma4(acc1, a1.z, w2); fma4(acc1, a1.w, w3);
            fma4(acc2, a2.x, w0); fma4(acc2, a2.y, w1); fma4(acc2, a2.z, w2); fma4(acc2, a2.w, w3);
            fma4(acc3, a3.x, w0); fma4(acc3, a3.y, w1); fma4(acc3, a3.z, w2); fma4(acc3, a3.w, w3);
        }
    }

    int nb = node0 + 4 * ty;
    if (nb + 0 < n) { float dv = dinv[nb + 0];
        float4 r; r.x = acc0.x * dv; r.y = acc0.y * dv; r.z = acc0.z * dv; r.w = acc0.w * dv;
        g4[(size_t)(nb + 0) * 16 + tx] = r; }
    if (nb + 1 < n) { float dv = dinv[nb + 1];
        float4 r; r.x = acc1.x * dv; r.y = acc1.y * dv; r.z = acc1.z * dv; r.w = acc1.w * dv;
        g4[(size_t)(nb + 1) * 16 + tx] = r; }
    if (nb + 2 < n) { float dv = dinv[nb + 2];
        float4 r; r.x = acc2.x * dv; r.y = acc2.y * dv; r.z = acc2.z * dv; r.w = acc2.w * dv;
        g4[(size_t)(nb + 2) * 16 + tx] = r; }
    if (nb + 3 < n) { float dv = dinv[nb + 3];
        float4 r; r.x = acc3.x * dv; r.y = acc3.y * dv; r.z = acc3.z * dv; r.w = acc3.w * dv;
        g4[(size_t)(nb + 3) * 16 + tx] = r; }
}

// agg[d] = dv_d * ( g[d] + sum_{s in N(d)} g[s] )
// float4 lanes: 16 lanes per row, 4 lane-groups fetch different rows, unroll 2.
__global__ __launch_bounds__(256) void k_gather(const int* __restrict__ off,
                                                const int* __restrict__ adj,
                                                const float* __restrict__ dinv,
                                                const float4* __restrict__ g4,
                                                float4* __restrict__ agg4, int n) {
    int node = blockIdx.x * 4 + (threadIdx.x >> 6);
    if (node >= n) return;
    int lane = threadIdx.x & 63;
    int grp = lane >> 4, sub = lane & 15;
    int a0 = off[node], a1 = off[node + 1];

    float ax = 0.f, ay = 0.f, az = 0.f, aw = 0.f;
    for (int a = a0; a < a1; a += 8) {
        int i0 = a + grp, i1 = a + 4 + grp;
        int s0 = adj[i0 < a1 ? i0 : a0];
        int s1 = adj[i1 < a1 ? i1 : a0];
        float4 x0 = g4[(size_t)s0 * 16 + sub];
        float4 x1 = g4[(size_t)s1 * 16 + sub];
        if (i0 < a1) { ax += x0.x; ay += x0.y; az += x0.z; aw += x0.w; }
        if (i1 < a1) { ax += x1.x; ay += x1.y; az += x1.z; aw += x1.w; }
    }
#pragma unroll
    for (int m = 16; m <= 32; m <<= 1) {
        ax += __shfl_xor(ax, m);
        ay += __shfl_xor(ay, m);
        az += __shfl_xor(az, m);
        aw += __shfl_xor(aw, m);
    }
    float4 self = g4[(size_t)node * 16 + sub];
    float dvv = dinv[node];
    if (lane < 16) {
        float4 r;
        r.x = (ax + self.x) * dvv;
        r.y = (ay + self.y) * dvv;
        r.z = (az + self.z) * dvv;
        r.w = (aw + self.w) * dvv;
        agg4[(size_t)node * 16 + sub] = r;
    }
}

// ---------- pool + fc ----------
__device__ __forceinline__ int lower_bound_batch(const int* __restrict__ batch, int n, int val) {
    int lo = 0, hi = n;
    while (lo < hi) {
        int mid = (lo + hi) >> 1;
        if (batch[mid] < val) lo = mid + 1; else hi = mid;
    }
    return lo;
}

__global__ void k_pool_part(const float* __restrict__ agg, const float* __restrict__ b3,
                            const int* __restrict__ batch, float* __restrict__ part, int n) {
    int b = blockIdx.x / PS;
    int s = blockIdx.x % PS;
    int lo = lower_bound_batch(batch, n, b);
    int hi = lower_bound_batch(batch, n, b + 1);
    int len = hi - lo;
    int c0 = lo + (int)((long long)len * s / PS);
    int c1 = lo + (int)((long long)len * (s + 1) / PS);

    int j = threadIdx.x & 63;
    int w = threadIdx.x >> 6;
    float bj = b3[j];
    float acc = 0.0f;
    for (int node = c0 + w; node < c1; node += 4)
        acc += fmaxf(agg[(size_t)node * DH + j] + bj, 0.0f);

    __shared__ float red[4][DH];
    red[w][j] = acc;
    __syncthreads();
    if (w == 0)
        part[(b * PS + s) * DH + j] = red[0][j] + red[1][j] + red[2][j] + red[3][j];
}

__global__ void k_fc(const float* __restrict__ part, const int* __restrict__ batch,
                     const float* __restrict__ Wfc, const float* __restrict__ bfc,
                     float* __restrict__ out, int n) {
    int b = blockIdx.x;
    int j = threadIdx.x;  // 64 threads = 1 wave
    int lo = lower_bound_batch(batch, n, b);
    int hi = lower_bound_batch(batch, n, b + 1);
    float c = fmaxf((float)(hi - lo), 1.0f);
    float p = 0.0f;
#pragma unroll
    for (int s = 0; s < PS; ++s) p += part[(b * PS + s) * DH + j];
    p = (p / c) * Wfc[j];
#pragma unroll
    for (int off = 32; off; off >>= 1) p += __shfl_down(p, off);
    if (j == 0) out[b] = p + bfc[0];
}

extern "C" void kernel_launch(void* const* d_in, const int* in_sizes, int n_in,
                              void* d_out, int out_size, void* d_ws, size_t ws_size,
                              hipStream_t stream) {
    const float* x    = (const float*)d_in[0];
    const int* ei     = (const int*)d_in[1];
    const int* batch  = (const int*)d_in[2];
    const float* W1   = (const float*)d_in[3];
    const float* b1   = (const float*)d_in[4];
    const float* W2   = (const float*)d_in[5];
    const float* b2   = (const float*)d_in[6];
    const float* W3   = (const float*)d_in[7];
    const float* b3   = (const float*)d_in[8];
    const float* Wfc  = (const float*)d_in[9];
    const float* bfc  = (const float*)d_in[10];
    float* out = (float*)d_out;

    const int n = in_sizes[0] / DI;  // 50000
    const int e = in_sizes[1] / 2;   // 800000
    const int* src = ei;
    const int* dst = ei + e;

    // workspace layout (all 4-byte elements; h/agg 16B-aligned for float4)
    float* dinv   = (float*)d_ws;               // n
    float* h      = dinv + n;                   // n*DH  (offset 200000B, 16B-aligned)
    float* agg    = h + (size_t)n * DH;         // n*DH
    float* part   = agg + (size_t)n * DH;       // NB*PS*DH
    int*   counts = (int*)(part + NB * PS * DH);// n
    int*   excl   = counts + n;                 // n
    int*   off    = excl + n;                   // n+1
    int*   cursor = off + n + 1;                // n
    int*   bsum   = cursor + n;                 // 256
    int*   boff   = bsum + 256;                 // 256
    int*   adj    = boff + 256;                 // e

    const int nb256 = (n + 255) / 256;
    const int eb256 = (e + 255) / 256;
    const int wb4   = (n + 3) / 4;    // 1 wave per node kernels
    const int gmb   = (n + 63) / 64;  // gemm blocks (64 nodes each)
    const int sg    = (n + SCB - 1) / SCB;

    // ---- CSR build (shared by all 3 layers) ----
    hipMemsetAsync(counts, 0, (size_t)n * sizeof(int), stream);
    k_count<<<eb256, 256, 0, stream>>>(dst, counts, e);
    k_scan1<<<sg, SCB, 0, stream>>>(counts, excl, bsum, n);
    k_scan2<<<1, 256, 0, stream>>>(bsum, boff, sg);
    k_scan3<<<nb256 + 1, 256, 0, stream>>>(counts, excl, boff, off, cursor, dinv, n, e);
    k_fill<<<eb256, 256, 0, stream>>>(src, dst, cursor, adj, e);
    k_sort<<<wb4, 256, 0, stream>>>(off, adj, n);

    // ---- layers ----
    k_matmul<DI, false><<<gmb, 256, 0, stream>>>((const float4*)x, (const float4*)W1,
                                                 nullptr, dinv, (float4*)h, n);
    k_gather<<<wb4, 256, 0, stream>>>(off, adj, dinv, (const float4*)h, (float4*)agg, n);
    k_matmul<DH, true><<<gmb, 256, 0, stream>>>((const float4*)agg, (const float4*)W2,
                                                (const float4*)b1, dinv, (float4*)h, n);
    k_gather<<<wb4, 256, 0, stream>>>(off, adj, dinv, (const float4*)h, (float4*)agg, n);
    k_matmul<DH, true><<<gmb, 256, 0, stream>>>((const float4*)agg, (const float4*)W3,
                                                (const float4*)b2, dinv, (float4*)h, n);
    k_gather<<<wb4, 256, 0, stream>>>(off, adj, dinv, (const float4*)h, (float4*)agg, n);

    // ---- pool + fc ----
    k_pool_part<<<NB * PS, 256, 0, stream>>>(agg, b3, batch, part, n);
    k_fc<<<NB, DH, 0, stream>>>(part, batch, Wfc, bfc, out, n);
}

// Round 7
// 292.616 us; speedup vs baseline: 3.6323x; 1.0368x over previous
//
#include <hip/hip_runtime.h>

// Problem dims (fixed by reference): N=50000, E=800000, D_IN=128, D_H=64, B=64
constexpr int DI = 128;
constexpr int DH = 64;
constexpr int NB = 64;
constexpr int PS = 8;    // pool split factor
constexpr int SCB = 256; // scan block size
constexpr int NXCD = 8;  // XCDs on MI355X; blockIdx%8 round-robins (perf heuristic only)

// ---------- CSR build ----------
__global__ void k_count(const int* __restrict__ dst, int* __restrict__ counts, int e) {
    int i = blockIdx.x * 256 + threadIdx.x;
    if (i < e) atomicAdd(&counts[dst[i]], 1);
}

// per-block exclusive scan; excl[i] = scan within block, bsum[b] = block total
__global__ void k_scan1(const int* __restrict__ counts, int* __restrict__ excl,
                        int* __restrict__ bsum, int n) {
    __shared__ int sd[SCB];
    int t = threadIdx.x;
    int i = blockIdx.x * SCB + t;
    int v = (i < n) ? counts[i] : 0;
    sd[t] = v;
    __syncthreads();
    for (int o = 1; o < SCB; o <<= 1) {
        int x = (t >= o) ? sd[t - o] : 0;
        __syncthreads();
        sd[t] += x;
        __syncthreads();
    }
    if (i < n) excl[i] = sd[t] - v;
    if (t == SCB - 1) bsum[blockIdx.x] = sd[t];
}

// single-block exclusive scan of block sums (grid-stride with carry)
__global__ void k_scan2(const int* __restrict__ bsum, int* __restrict__ boff, int g) {
    __shared__ int sd[256];
    __shared__ int carry;
    int t = threadIdx.x;
    if (t == 0) carry = 0;
    __syncthreads();
    for (int base = 0; base < g; base += 256) {
        int idx = base + t;
        int v = (idx < g) ? bsum[idx] : 0;
        sd[t] = v;
        __syncthreads();
        for (int o = 1; o < 256; o <<= 1) {
            int x = (t >= o) ? sd[t - o] : 0;
            __syncthreads();
            sd[t] += x;
            __syncthreads();
        }
        if (idx < g) boff[idx] = sd[t] - v + carry;
        __syncthreads();
        if (t == 0) carry += sd[255];
        __syncthreads();
    }
}

// off = global exclusive scan; cursor = copy; dinv = 1/sqrt(1+indeg)
__global__ void k_scan3(const int* __restrict__ counts, const int* __restrict__ excl,
                        const int* __restrict__ boff, int* __restrict__ off,
                        int* __restrict__ cursor, float* __restrict__ dinv, int n, int e) {
    int i = blockIdx.x * 256 + threadIdx.x;
    if (i < n) {
        int o = excl[i] + boff[i / SCB];
        off[i] = o;
        cursor[i] = o;
        dinv[i] = 1.0f / sqrtf(1.0f + (float)counts[i]);
    }
    if (i == n) off[n] = e;
}

// XCD-partitioned fill: 8-way replicated edge scan; block handles only dst in
// its partition (part = blockIdx&7 -> one XCD per partition under round-robin
// dispatch). Each adj cacheline is then written by a SINGLE XCD -> one clean
// writeback instead of 8 partial-line write-throughs (round-6: 52MB HBM writes
// for a 3.2MB array). Correct under ANY block->XCD mapping.
__global__ void k_fill(const int* __restrict__ src, const int* __restrict__ dst,
                       int* __restrict__ cursor, int* __restrict__ adj,
                       int e, int chunk) {
    int part = blockIdx.x & (NXCD - 1);
    int i = (blockIdx.x >> 3) * 256 + threadIdx.x;
    if (i >= e) return;
    int d = dst[i];
    int plo = part * chunk;
    if (d >= plo && d < plo + chunk) {
        int p = atomicAdd(&cursor[d], 1);
        adj[p] = src[i];
    }
}

// Wave-parallel rank sort: one wave per node bucket (deterministic result:
// tied keys are identical values).
__global__ void k_sort(const int* __restrict__ off, int* __restrict__ adj, int n) {
    int node = blockIdx.x * 4 + (threadIdx.x >> 6);
    if (node >= n) return;
    int lane = threadIdx.x & 63;
    int a0 = off[node], a1 = off[node + 1];
    int deg = a1 - a0;
    if (deg <= 1) return;
    if (deg <= 64) {
        int key = (lane < deg) ? adj[a0 + lane] : 0x7fffffff;
        int rank = 0;
        for (int m = 0; m < deg; ++m) {
            int km = __shfl(key, m);
            rank += (km < key) || (km == key && m < lane);
        }
        if (lane < deg) adj[a0 + rank] = key;
    } else if (lane == 0) {  // fallback, astronomically rare for random graphs
        for (int i = a0 + 1; i < a1; ++i) {
            int key = adj[i];
            int j = i - 1;
            while (j >= a0 && adj[j] > key) { adj[j + 1] = adj[j]; --j; }
            adj[j + 1] = key;
        }
    }
}

// ---------- layers ----------
__device__ __forceinline__ void fma4(float4& acc, float s, const float4& w) {
    acc.x = fmaf(s, w.x, acc.x);
    acc.y = fmaf(s, w.y, acc.y);
    acc.z = fmaf(s, w.z, acc.z);
    acc.w = fmaf(s, w.w, acc.w);
}

// g = (act(in) @ W) * dinv, LDS-tiled register-blocked GEMM.
// Block: 64 nodes x 64 feats, 256 threads as 16x16, 4x4 outputs/thread.
template <int K, bool RELU>
__global__ __launch_bounds__(256) void k_matmul(const float4* __restrict__ in4,
                                                const float4* __restrict__ W4,
                                                const float4* __restrict__ b4,
                                                const float* __restrict__ dinv,
                                                float4* __restrict__ g4, int n) {
    __shared__ float4 Wl[K * 16];    // [K][64] floats
    __shared__ float4 Al[64 * 17];   // [64][68] floats (pad 4)
    const int t = threadIdx.x;
    for (int i = t; i < K * 16; i += 256) Wl[i] = W4[i];

    const int tx = t & 15;          // feature group: 4*tx .. 4*tx+3
    const int ty = t >> 4;          // node group:    4*ty .. 4*ty+3
    const int node0 = blockIdx.x * 64;
    constexpr int K4 = K / 4;

    float4 acc0 = {0,0,0,0}, acc1 = {0,0,0,0}, acc2 = {0,0,0,0}, acc3 = {0,0,0,0};

#pragma unroll
    for (int ph = 0; ph < K / 64; ++ph) {
        __syncthreads();  // also covers initial W staging
#pragma unroll
        for (int s = 0; s < 4; ++s) {
            int i = t + s * 256;          // 64 rows x 16 float4
            int r = i >> 4, k4 = i & 15;
            int node = node0 + r;
            if (node >= n) node = n - 1;  // clamp (dup rows harmless)
            float4 v = in4[(size_t)node * K4 + ph * 16 + k4];
            if (RELU) {
                float4 bb = b4[ph * 16 + k4];
                v.x = fmaxf(v.x + bb.x, 0.f);
                v.y = fmaxf(v.y + bb.y, 0.f);
                v.z = fmaxf(v.z + bb.z, 0.f);
                v.w = fmaxf(v.w + bb.w, 0.f);
            }
            Al[r * 17 + k4] = v;
        }
        __syncthreads();
#pragma unroll 4
        for (int k4 = 0; k4 < 16; ++k4) {
            float4 a0 = Al[(4 * ty + 0) * 17 + k4];
            float4 a1 = Al[(4 * ty + 1) * 17 + k4];
            float4 a2 = Al[(4 * ty + 2) * 17 + k4];
            float4 a3 = Al[(4 * ty + 3) * 17 + k4];
            const float4* wrow = &Wl[(ph * 64 + 4 * k4) * 16 + tx];
            float4 w0 = wrow[0];
            float4 w1 = wrow[16];
            float4 w2 = wrow[32];
            float4 w3 = wrow[48];
            fma4(acc0, a0.x, w0); fma4(acc0, a0.y, w1); fma4(acc0, a0.z, w2); fma4(acc0, a0.w, w3);
            fma4(acc1, a1.x, w0); fma4(acc1, a1.y, w1); fma4(acc1, a1.z, w2); fma4(acc1, a1.w, w3);
            fma4(acc2, a2.x, w0); fma4(acc2, a2.y, w1); fma4(acc2, a2.z, w2); fma4(acc2, a2.w, w3);
            fma4(acc3, a3.x, w0); fma4(acc3, a3.y, w1); fma4(acc3, a3.z, w2); fma4(acc3, a3.w, w3);
        }
    }

    int nb = node0 + 4 * ty;
    if (nb + 0 < n) { float dv = dinv[nb + 0];
        float4 r; r.x = acc0.x * dv; r.y = acc0.y * dv; r.z = acc0.z * dv; r.w = acc0.w * dv;
        g4[(size_t)(nb + 0) * 16 + tx] = r; }
    if (nb + 1 < n) { float dv = dinv[nb + 1];
        float4 r; r.x = acc1.x * dv; r.y = acc1.y * dv; r.z = acc1.z * dv; r.w = acc1.w * dv;
        g4[(size_t)(nb + 1) * 16 + tx] = r; }
    if (nb + 2 < n) { float dv = dinv[nb + 2];
        float4 r; r.x = acc2.x * dv; r.y = acc2.y * dv; r.z = acc2.z * dv; r.w = acc2.w * dv;
        g4[(size_t)(nb + 2) * 16 + tx] = r; }
    if (nb + 3 < n) { float dv = dinv[nb + 3];
        float4 r; r.x = acc3.x * dv; r.y = acc3.y * dv; r.z = acc3.z * dv; r.w = acc3.w * dv;
        g4[(size_t)(nb + 3) * 16 + tx] = r; }
}

// agg[d] = dv_d * ( g[d] + sum_{s in N(d)} g[s] )
// 16 lanes per row; 4 lane-groups x unroll 4 -> 16 rows in flight per wave.
// Row loads PREDICATED (group-uniform guard -> masked groups issue no
// requests; round-6's clamped loads wasted ~25% row traffic on tails).
__global__ __launch_bounds__(256) void k_gather(const int* __restrict__ off,
                                                const int* __restrict__ adj,
                                                const float* __restrict__ dinv,
                                                const float4* __restrict__ g4,
                                                float4* __restrict__ agg4, int n) {
    int node = blockIdx.x * 4 + (threadIdx.x >> 6);
    if (node >= n) return;
    int lane = threadIdx.x & 63;
    int grp = lane >> 4, sub = lane & 15;
    int a0 = off[node], a1 = off[node + 1];

    float4 self = g4[(size_t)node * 16 + sub];  // hoisted: overlaps loop latency
    float dvv = dinv[node];

    float ax = 0.f, ay = 0.f, az = 0.f, aw = 0.f;
    for (int a = a0; a < a1; a += 16) {
#pragma unroll
        for (int q = 0; q < 4; ++q) {
            int i = a + 4 * q + grp;
            if (i < a1) {  // uniform per 16-lane group
                int s = adj[i];
                float4 v = g4[(size_t)s * 16 + sub];
                ax += v.x; ay += v.y; az += v.z; aw += v.w;
            }
        }
    }
#pragma unroll
    for (int m = 16; m <= 32; m <<= 1) {
        ax += __shfl_xor(ax, m);
        ay += __shfl_xor(ay, m);
        az += __shfl_xor(az, m);
        aw += __shfl_xor(aw, m);
    }
    if (lane < 16) {
        float4 r;
        r.x = (ax + self.x) * dvv;
        r.y = (ay + self.y) * dvv;
        r.z = (az + self.z) * dvv;
        r.w = (aw + self.w) * dvv;
        agg4[(size_t)node * 16 + sub] = r;
    }
}

// ---------- pool + fc ----------
__device__ __forceinline__ int lower_bound_batch(const int* __restrict__ batch, int n, int val) {
    int lo = 0, hi = n;
    while (lo < hi) {
        int mid = (lo + hi) >> 1;
        if (batch[mid] < val) lo = mid + 1; else hi = mid;
    }
    return lo;
}

__global__ void k_pool_part(const float* __restrict__ agg, const float* __restrict__ b3,
                            const int* __restrict__ batch, float* __restrict__ part, int n) {
    int b = blockIdx.x / PS;
    int s = blockIdx.x % PS;
    int lo = lower_bound_batch(batch, n, b);
    int hi = lower_bound_batch(batch, n, b + 1);
    int len = hi - lo;
    int c0 = lo + (int)((long long)len * s / PS);
    int c1 = lo + (int)((long long)len * (s + 1) / PS);

    int j = threadIdx.x & 63;
    int w = threadIdx.x >> 6;
    float bj = b3[j];
    float acc = 0.0f;
    for (int node = c0 + w; node < c1; node += 4)
        acc += fmaxf(agg[(size_t)node * DH + j] + bj, 0.0f);

    __shared__ float red[4][DH];
    red[w][j] = acc;
    __syncthreads();
    if (w == 0)
        part[(b * PS + s) * DH + j] = red[0][j] + red[1][j] + red[2][j] + red[3][j];
}

__global__ void k_fc(const float* __restrict__ part, const int* __restrict__ batch,
                     const float* __restrict__ Wfc, const float* __restrict__ bfc,
                     float* __restrict__ out, int n) {
    int b = blockIdx.x;
    int j = threadIdx.x;  // 64 threads = 1 wave
    int lo = lower_bound_batch(batch, n, b);
    int hi = lower_bound_batch(batch, n, b + 1);
    float c = fmaxf((float)(hi - lo), 1.0f);
    float p = 0.0f;
#pragma unroll
    for (int s = 0; s < PS; ++s) p += part[(b * PS + s) * DH + j];
    p = (p / c) * Wfc[j];
#pragma unroll
    for (int off = 32; off; off >>= 1) p += __shfl_down(p, off);
    if (j == 0) out[b] = p + bfc[0];
}

extern "C" void kernel_launch(void* const* d_in, const int* in_sizes, int n_in,
                              void* d_out, int out_size, void* d_ws, size_t ws_size,
                              hipStream_t stream) {
    const float* x    = (const float*)d_in[0];
    const int* ei     = (const int*)d_in[1];
    const int* batch  = (const int*)d_in[2];
    const float* W1   = (const float*)d_in[3];
    const float* b1   = (const float*)d_in[4];
    const float* W2   = (const float*)d_in[5];
    const float* b2   = (const float*)d_in[6];
    const float* W3   = (const float*)d_in[7];
    const float* b3   = (const float*)d_in[8];
    const float* Wfc  = (const float*)d_in[9];
    const float* bfc  = (const float*)d_in[10];
    float* out = (float*)d_out;

    const int n = in_sizes[0] / DI;  // 50000
    const int e = in_sizes[1] / 2;   // 800000
    const int* src = ei;
    const int* dst = ei + e;

    // workspace layout (all 4-byte elements; h/agg 16B-aligned for float4)
    float* dinv   = (float*)d_ws;               // n
    float* h      = dinv + n;                   // n*DH  (offset 200000B, 16B-aligned)
    float* agg    = h + (size_t)n * DH;         // n*DH
    float* part   = agg + (size_t)n * DH;       // NB*PS*DH
    int*   counts = (int*)(part + NB * PS * DH);// n
    int*   excl   = counts + n;                 // n
    int*   off    = excl + n;                   // n+1
    int*   cursor = off + n + 1;                // n
    int*   bsum   = cursor + n;                 // 256
    int*   boff   = bsum + 256;                 // 256
    int*   adj    = boff + 256;                 // e

    const int nb256 = (n + 255) / 256;
    const int eb256 = (e + 255) / 256;
    const int wb4   = (n + 3) / 4;    // 1 wave per node kernels
    const int gmb   = (n + 63) / 64;  // gemm blocks (64 nodes each)
    const int sg    = (n + SCB - 1) / SCB;
    const int chunk = (n + NXCD - 1) / NXCD;  // dst-partition size (6250)

    // ---- CSR build (shared by all 3 layers) ----
    hipMemsetAsync(counts, 0, (size_t)n * sizeof(int), stream);
    k_count<<<eb256, 256, 0, stream>>>(dst, counts, e);
    k_scan1<<<sg, SCB, 0, stream>>>(counts, excl, bsum, n);
    k_scan2<<<1, 256, 0, stream>>>(bsum, boff, sg);
    k_scan3<<<nb256 + 1, 256, 0, stream>>>(counts, excl, boff, off, cursor, dinv, n, e);
    k_fill<<<eb256 * NXCD, 256, 0, stream>>>(src, dst, cursor, adj, e, chunk);
    k_sort<<<wb4, 256, 0, stream>>>(off, adj, n);

    // ---- layers ----
    k_matmul<DI, false><<<gmb, 256, 0, stream>>>((const float4*)x, (const float4*)W1,
                                                 nullptr, dinv, (float4*)h, n);
    k_gather<<<wb4, 256, 0, stream>>>(off, adj, dinv, (const float4*)h, (float4*)agg, n);
    k_matmul<DH, true><<<gmb, 256, 0, stream>>>((const float4*)agg, (const float4*)W2,
                                                (const float4*)b1, dinv, (float4*)h, n);
    k_gather<<<wb4, 256, 0, stream>>>(off, adj, dinv, (const float4*)h, (float4*)agg, n);
    k_matmul<DH, true><<<gmb, 256, 0, stream>>>((const float4*)agg, (const float4*)W3,
                                                (const float4*)b2, dinv, (float4*)h, n);
    k_gather<<<wb4, 256, 0, stream>>>(off, adj, dinv, (const float4*)h, (float4*)agg, n);

    // ---- pool + fc ----
    k_pool_part<<<NB * PS, 256, 0, stream>>>(agg, b3, batch, part, n);
    k_fc<<<NB, DH, 0, stream>>>(part, batch, Wfc, bfc, out, n);
}

// Round 8
// 292.470 us; speedup vs baseline: 3.6341x; 1.0005x over previous
//
#include <hip/hip_runtime.h>

// Problem dims (fixed by reference): N=50000, E=800000, D_IN=128, D_H=64, B=64
constexpr int DI = 128;
constexpr int DH = 64;
constexpr int NB = 64;
constexpr int PS = 8;    // pool split factor
constexpr int SCB = 256; // scan block size
constexpr int NXCD = 8;  // XCDs on MI355X; blockIdx%8 round-robins (perf heuristic only)

// Custom zero-fill: hipMemsetAsync's captured fillBufferAligned ran 42us for
// 200KB (tiny latency-bound config, 14% of total). int4 grid-stride, ~2-3us.
__global__ void k_zero(int4* __restrict__ p, int nw4) {
    int i = blockIdx.x * 256 + threadIdx.x;
    if (i < nw4) p[i] = make_int4(0, 0, 0, 0);
}

// ---------- CSR build ----------
__global__ void k_count(const int* __restrict__ dst, int* __restrict__ counts, int e) {
    int i = blockIdx.x * 256 + threadIdx.x;
    if (i < e) atomicAdd(&counts[dst[i]], 1);
}

// per-block exclusive scan; excl[i] = scan within block, bsum[b] = block total
__global__ void k_scan1(const int* __restrict__ counts, int* __restrict__ excl,
                        int* __restrict__ bsum, int n) {
    __shared__ int sd[SCB];
    int t = threadIdx.x;
    int i = blockIdx.x * SCB + t;
    int v = (i < n) ? counts[i] : 0;
    sd[t] = v;
    __syncthreads();
    for (int o = 1; o < SCB; o <<= 1) {
        int x = (t >= o) ? sd[t - o] : 0;
        __syncthreads();
        sd[t] += x;
        __syncthreads();
    }
    if (i < n) excl[i] = sd[t] - v;
    if (t == SCB - 1) bsum[blockIdx.x] = sd[t];
}

// single-block exclusive scan of block sums (grid-stride with carry)
__global__ void k_scan2(const int* __restrict__ bsum, int* __restrict__ boff, int g) {
    __shared__ int sd[256];
    __shared__ int carry;
    int t = threadIdx.x;
    if (t == 0) carry = 0;
    __syncthreads();
    for (int base = 0; base < g; base += 256) {
        int idx = base + t;
        int v = (idx < g) ? bsum[idx] : 0;
        sd[t] = v;
        __syncthreads();
        for (int o = 1; o < 256; o <<= 1) {
            int x = (t >= o) ? sd[t - o] : 0;
            __syncthreads();
            sd[t] += x;
            __syncthreads();
        }
        if (idx < g) boff[idx] = sd[t] - v + carry;
        __syncthreads();
        if (t == 0) carry += sd[255];
        __syncthreads();
    }
}

// off = global exclusive scan; cursor = copy; dinv = 1/sqrt(1+indeg)
__global__ void k_scan3(const int* __restrict__ counts, const int* __restrict__ excl,
                        const int* __restrict__ boff, int* __restrict__ off,
                        int* __restrict__ cursor, float* __restrict__ dinv, int n, int e) {
    int i = blockIdx.x * 256 + threadIdx.x;
    if (i < n) {
        int o = excl[i] + boff[i / SCB];
        off[i] = o;
        cursor[i] = o;
        dinv[i] = 1.0f / sqrtf(1.0f + (float)counts[i]);
    }
    if (i == n) off[n] = e;
}

// XCD-partitioned fill: 8-way replicated edge scan; block handles only dst in
// its partition (part = blockIdx&7 -> one XCD per partition under round-robin
// dispatch). Each adj cacheline is then written by a SINGLE XCD -> one clean
// writeback instead of 8 partial-line write-throughs. Correct under ANY
// block->XCD mapping.
__global__ void k_fill(const int* __restrict__ src, const int* __restrict__ dst,
                       int* __restrict__ cursor, int* __restrict__ adj,
                       int e, int chunk) {
    int part = blockIdx.x & (NXCD - 1);
    int i = (blockIdx.x >> 3) * 256 + threadIdx.x;
    if (i >= e) return;
    int d = dst[i];
    int plo = part * chunk;
    if (d >= plo && d < plo + chunk) {
        int p = atomicAdd(&cursor[d], 1);
        adj[p] = src[i];
    }
}

// Wave-parallel rank sort: one wave per node bucket (deterministic result:
// tied keys are identical values).
__global__ void k_sort(const int* __restrict__ off, int* __restrict__ adj, int n) {
    int node = blockIdx.x * 4 + (threadIdx.x >> 6);
    if (node >= n) return;
    int lane = threadIdx.x & 63;
    int a0 = off[node], a1 = off[node + 1];
    int deg = a1 - a0;
    if (deg <= 1) return;
    if (deg <= 64) {
        int key = (lane < deg) ? adj[a0 + lane] : 0x7fffffff;
        int rank = 0;
        for (int m = 0; m < deg; ++m) {
            int km = __shfl(key, m);
            rank += (km < key) || (km == key && m < lane);
        }
        if (lane < deg) adj[a0 + rank] = key;
    } else if (lane == 0) {  // fallback, astronomically rare for random graphs
        for (int i = a0 + 1; i < a1; ++i) {
            int key = adj[i];
            int j = i - 1;
            while (j >= a0 && adj[j] > key) { adj[j + 1] = adj[j]; --j; }
            adj[j + 1] = key;
        }
    }
}

// ---------- layers ----------
__device__ __forceinline__ void fma4(float4& acc, float s, const float4& w) {
    acc.x = fmaf(s, w.x, acc.x);
    acc.y = fmaf(s, w.y, acc.y);
    acc.z = fmaf(s, w.z, acc.z);
    acc.w = fmaf(s, w.w, acc.w);
}

// g = (act(in) @ W) * dinv, LDS-tiled register-blocked GEMM.
// Block: 64 nodes x 64 feats, 256 threads as 16x16, 4x4 outputs/thread.
template <int K, bool RELU>
__global__ __launch_bounds__(256) void k_matmul(const float4* __restrict__ in4,
                                                const float4* __restrict__ W4,
                                                const float4* __restrict__ b4,
                                                const float* __restrict__ dinv,
                                                float4* __restrict__ g4, int n) {
    __shared__ float4 Wl[K * 16];    // [K][64] floats
    __shared__ float4 Al[64 * 17];   // [64][68] floats (pad 4)
    const int t = threadIdx.x;
    for (int i = t; i < K * 16; i += 256) Wl[i] = W4[i];

    const int tx = t & 15;          // feature group: 4*tx .. 4*tx+3
    const int ty = t >> 4;          // node group:    4*ty .. 4*ty+3
    const int node0 = blockIdx.x * 64;
    constexpr int K4 = K / 4;

    float4 acc0 = {0,0,0,0}, acc1 = {0,0,0,0}, acc2 = {0,0,0,0}, acc3 = {0,0,0,0};

#pragma unroll
    for (int ph = 0; ph < K / 64; ++ph) {
        __syncthreads();  // also covers initial W staging
#pragma unroll
        for (int s = 0; s < 4; ++s) {
            int i = t + s * 256;          // 64 rows x 16 float4
            int r = i >> 4, k4 = i & 15;
            int node = node0 + r;
            if (node >= n) node = n - 1;  // clamp (dup rows harmless)
            float4 v = in4[(size_t)node * K4 + ph * 16 + k4];
            if (RELU) {
                float4 bb = b4[ph * 16 + k4];
                v.x = fmaxf(v.x + bb.x, 0.f);
                v.y = fmaxf(v.y + bb.y, 0.f);
                v.z = fmaxf(v.z + bb.z, 0.f);
                v.w = fmaxf(v.w + bb.w, 0.f);
            }
            Al[r * 17 + k4] = v;
        }
        __syncthreads();
#pragma unroll 4
        for (int k4 = 0; k4 < 16; ++k4) {
            float4 a0 = Al[(4 * ty + 0) * 17 + k4];
            float4 a1 = Al[(4 * ty + 1) * 17 + k4];
            float4 a2 = Al[(4 * ty + 2) * 17 + k4];
            float4 a3 = Al[(4 * ty + 3) * 17 + k4];
            const float4* wrow = &Wl[(ph * 64 + 4 * k4) * 16 + tx];
            float4 w0 = wrow[0];
            float4 w1 = wrow[16];
            float4 w2 = wrow[32];
            float4 w3 = wrow[48];
            fma4(acc0, a0.x, w0); fma4(acc0, a0.y, w1); fma4(acc0, a0.z, w2); fma4(acc0, a0.w, w3);
            fma4(acc1, a1.x, w0); fma4(acc1, a1.y, w1); fma4(acc1, a1.z, w2); fma4(acc1, a1.w, w3);
            fma4(acc2, a2.x, w0); fma4(acc2, a2.y, w1); fma4(acc2, a2.z, w2); fma4(acc2, a2.w, w3);
            fma4(acc3, a3.x, w0); fma4(acc3, a3.y, w1); fma4(acc3, a3.z, w2); fma4(acc3, a3.w, w3);
        }
    }

    int nb = node0 + 4 * ty;
    if (nb + 0 < n) { float dv = dinv[nb + 0];
        float4 r; r.x = acc0.x * dv; r.y = acc0.y * dv; r.z = acc0.z * dv; r.w = acc0.w * dv;
        g4[(size_t)(nb + 0) * 16 + tx] = r; }
    if (nb + 1 < n) { float dv = dinv[nb + 1];
        float4 r; r.x = acc1.x * dv; r.y = acc1.y * dv; r.z = acc1.z * dv; r.w = acc1.w * dv;
        g4[(size_t)(nb + 1) * 16 + tx] = r; }
    if (nb + 2 < n) { float dv = dinv[nb + 2];
        float4 r; r.x = acc2.x * dv; r.y = acc2.y * dv; r.z = acc2.z * dv; r.w = acc2.w * dv;
        g4[(size_t)(nb + 2) * 16 + tx] = r; }
    if (nb + 3 < n) { float dv = dinv[nb + 3];
        float4 r; r.x = acc3.x * dv; r.y = acc3.y * dv; r.z = acc3.z * dv; r.w = acc3.w * dv;
        g4[(size_t)(nb + 3) * 16 + tx] = r; }
}

// agg[d] = dv_d * ( g[d] + sum_{s in N(d)} g[s] )
// 16 lanes per row; 4 lane-groups x unroll 4 -> 16 rows in flight per wave.
// Row loads predicated (group-uniform guard -> masked groups issue no requests).
__global__ __launch_bounds__(256) void k_gather(const int* __restrict__ off,
                                                const int* __restrict__ adj,
                                                const float* __restrict__ dinv,
                                                const float4* __restrict__ g4,
                                                float4* __restrict__ agg4, int n) {
    int node = blockIdx.x * 4 + (threadIdx.x >> 6);
    if (node >= n) return;
    int lane = threadIdx.x & 63;
    int grp = lane >> 4, sub = lane & 15;
    int a0 = off[node], a1 = off[node + 1];

    float4 self = g4[(size_t)node * 16 + sub];  // hoisted: overlaps loop latency
    float dvv = dinv[node];

    float ax = 0.f, ay = 0.f, az = 0.f, aw = 0.f;
    for (int a = a0; a < a1; a += 16) {
#pragma unroll
        for (int q = 0; q < 4; ++q) {
            int i = a + 4 * q + grp;
            if (i < a1) {  // uniform per 16-lane group
                int s = adj[i];
                float4 v = g4[(size_t)s * 16 + sub];
                ax += v.x; ay += v.y; az += v.z; aw += v.w;
            }
        }
    }
#pragma unroll
    for (int m = 16; m <= 32; m <<= 1) {
        ax += __shfl_xor(ax, m);
        ay += __shfl_xor(ay, m);
        az += __shfl_xor(az, m);
        aw += __shfl_xor(aw, m);
    }
    if (lane < 16) {
        float4 r;
        r.x = (ax + self.x) * dvv;
        r.y = (ay + self.y) * dvv;
        r.z = (az + self.z) * dvv;
        r.w = (aw + self.w) * dvv;
        agg4[(size_t)node * 16 + sub] = r;
    }
}

// ---------- pool + fc ----------
__device__ __forceinline__ int lower_bound_batch(const int* __restrict__ batch, int n, int val) {
    int lo = 0, hi = n;
    while (lo < hi) {
        int mid = (lo + hi) >> 1;
        if (batch[mid] < val) lo = mid + 1; else hi = mid;
    }
    return lo;
}

__global__ void k_pool_part(const float* __restrict__ agg, const float* __restrict__ b3,
                            const int* __restrict__ batch, float* __restrict__ part, int n) {
    int b = blockIdx.x / PS;
    int s = blockIdx.x % PS;
    int lo = lower_bound_batch(batch, n, b);
    int hi = lower_bound_batch(batch, n, b + 1);
    int len = hi - lo;
    int c0 = lo + (int)((long long)len * s / PS);
    int c1 = lo + (int)((long long)len * (s + 1) / PS);

    int j = threadIdx.x & 63;
    int w = threadIdx.x >> 6;
    float bj = b3[j];
    float acc = 0.0f;
    for (int node = c0 + w; node < c1; node += 4)
        acc += fmaxf(agg[(size_t)node * DH + j] + bj, 0.0f);

    __shared__ float red[4][DH];
    red[w][j] = acc;
    __syncthreads();
    if (w == 0)
        part[(b * PS + s) * DH + j] = red[0][j] + red[1][j] + red[2][j] + red[3][j];
}

__global__ void k_fc(const float* __restrict__ part, const int* __restrict__ batch,
                     const float* __restrict__ Wfc, const float* __restrict__ bfc,
                     float* __restrict__ out, int n) {
    int b = blockIdx.x;
    int j = threadIdx.x;  // 64 threads = 1 wave
    int lo = lower_bound_batch(batch, n, b);
    int hi = lower_bound_batch(batch, n, b + 1);
    float c = fmaxf((float)(hi - lo), 1.0f);
    float p = 0.0f;
#pragma unroll
    for (int s = 0; s < PS; ++s) p += part[(b * PS + s) * DH + j];
    p = (p / c) * Wfc[j];
#pragma unroll
    for (int off = 32; off; off >>= 1) p += __shfl_down(p, off);
    if (j == 0) out[b] = p + bfc[0];
}

extern "C" void kernel_launch(void* const* d_in, const int* in_sizes, int n_in,
                              void* d_out, int out_size, void* d_ws, size_t ws_size,
                              hipStream_t stream) {
    const float* x    = (const float*)d_in[0];
    const int* ei     = (const int*)d_in[1];
    const int* batch  = (const int*)d_in[2];
    const float* W1   = (const float*)d_in[3];
    const float* b1   = (const float*)d_in[4];
    const float* W2   = (const float*)d_in[5];
    const float* b2   = (const float*)d_in[6];
    const float* W3   = (const float*)d_in[7];
    const float* b3   = (const float*)d_in[8];
    const float* Wfc  = (const float*)d_in[9];
    const float* bfc  = (const float*)d_in[10];
    float* out = (float*)d_out;

    const int n = in_sizes[0] / DI;  // 50000
    const int e = in_sizes[1] / 2;   // 800000
    const int* src = ei;
    const int* dst = ei + e;

    // workspace layout (all 4-byte elements; h/agg 16B-aligned for float4)
    float* dinv   = (float*)d_ws;               // n
    float* h      = dinv + n;                   // n*DH  (offset 200000B, 16B-aligned)
    float* agg    = h + (size_t)n * DH;         // n*DH
    float* part   = agg + (size_t)n * DH;       // NB*PS*DH
    int*   counts = (int*)(part + NB * PS * DH);// n (16B-aligned: all prior sizes %4==0)
    int*   excl   = counts + n;                 // n
    int*   off    = excl + n;                   // n+1
    int*   cursor = off + n + 1;                // n
    int*   bsum   = cursor + n;                 // 256
    int*   boff   = bsum + 256;                 // 256
    int*   adj    = boff + 256;                 // e

    const int nb256 = (n + 255) / 256;
    const int eb256 = (e + 255) / 256;
    const int wb4   = (n + 3) / 4;    // 1 wave per node kernels
    const int gmb   = (n + 63) / 64;  // gemm blocks (64 nodes each)
    const int sg    = (n + SCB - 1) / SCB;
    const int chunk = (n + NXCD - 1) / NXCD;  // dst-partition size (6250)
    const int zw4   = n / 4;          // counts int4 words (50000 % 4 == 0)

    // ---- CSR build (shared by all 3 layers) ----
    k_zero<<<(zw4 + 255) / 256, 256, 0, stream>>>((int4*)counts, zw4);
    k_count<<<eb256, 256, 0, stream>>>(dst, counts, e);
    k_scan1<<<sg, SCB, 0, stream>>>(counts, excl, bsum, n);
    k_scan2<<<1, 256, 0, stream>>>(bsum, boff, sg);
    k_scan3<<<nb256 + 1, 256, 0, stream>>>(counts, excl, boff, off, cursor, dinv, n, e);
    k_fill<<<eb256 * NXCD, 256, 0, stream>>>(src, dst, cursor, adj, e, chunk);
    k_sort<<<wb4, 256, 0, stream>>>(off, adj, n);

    // ---- layers ----
    k_matmul<DI, false><<<gmb, 256, 0, stream>>>((const float4*)x, (const float4*)W1,
                                                 nullptr, dinv, (float4*)h, n);
    k_gather<<<wb4, 256, 0, stream>>>(off, adj, dinv, (const float4*)h, (float4*)agg, n);
    k_matmul<DH, true><<<gmb, 256, 0, stream>>>((const float4*)agg, (const float4*)W2,
                                                (const float4*)b1, dinv, (float4*)h, n);
    k_gather<<<wb4, 256, 0, stream>>>(off, adj, dinv, (const float4*)h, (float4*)agg, n);
    k_matmul<DH, true><<<gmb, 256, 0, stream>>>((const float4*)agg, (const float4*)W3,
                                                (const float4*)b2, dinv, (float4*)h, n);
    k_gather<<<wb4, 256, 0, stream>>>(off, adj, dinv, (const float4*)h, (float4*)agg, n);

    // ---- pool + fc ----
    k_pool_part<<<NB * PS, 256, 0, stream>>>(agg, b3, batch, part, n);
    k_fc<<<NB, DH, 0, stream>>>(part, batch, Wfc, bfc, out, n);
}